// Round 1
// baseline (1785.463 us; speedup 1.0000x reference)
//
#include <hip/hip_runtime.h>
#include <math.h>

#define NHEAD 8
#define DKD 64
#define DMODEL 512
#define LSEQ 1024
#define NB 8
#define NBL 8192          // B*L

// ---------------------------------------------------------------------------
// Generic fp32 GEMM: C[M,N] = A[M,K] @ B[K,N] + bias[N]  (+resid) (+relu)
// scatter!=0: write to q/k/v layout [B,H,L,DK] instead of row-major.
// 64x64 tile, 256 threads, 4x4 per thread, BK=16. LDS padded to 68 floats/row.
// ---------------------------------------------------------------------------
__global__ __launch_bounds__(256) void gemm_kernel(
    const float* __restrict__ A, const float* __restrict__ B,
    const float* __restrict__ bias, const float* __restrict__ resid,
    float* __restrict__ C, int M, int N, int K, int relu, int scatter)
{
    __shared__ float As[16][68];   // [k][m]  (A tile transposed)
    __shared__ float Bs[16][68];   // [k][n]

    const int t  = threadIdx.x;
    const int tx = t & 15, ty = t >> 4;
    const int rowBase = blockIdx.y * 64;
    const int colBase = blockIdx.x * 64;

    float acc[4][4] = {};

    const float* Ab = A + (size_t)(rowBase + (t >> 2)) * K + (t & 3) * 4;
    const float* Bb = B + (size_t)(t >> 4) * N + colBase + (t & 15) * 4;

    for (int k0 = 0; k0 < K; k0 += 16) {
        float4 av = *(const float4*)(Ab + k0);
        float4 bv = *(const float4*)(Bb + (size_t)k0 * N);
        __syncthreads();
        {
            int ar = t >> 2, ak = (t & 3) * 4;
            As[ak + 0][ar] = av.x;
            As[ak + 1][ar] = av.y;
            As[ak + 2][ar] = av.z;
            As[ak + 3][ar] = av.w;
            *(float4*)&Bs[t >> 4][(t & 15) * 4] = bv;
        }
        __syncthreads();
        #pragma unroll
        for (int kk = 0; kk < 16; ++kk) {
            float4 a4 = *(const float4*)&As[kk][ty * 4];
            float4 b4 = *(const float4*)&Bs[kk][tx * 4];
            float a[4] = {a4.x, a4.y, a4.z, a4.w};
            float b[4] = {b4.x, b4.y, b4.z, b4.w};
            #pragma unroll
            for (int i = 0; i < 4; ++i)
                #pragma unroll
                for (int j = 0; j < 4; ++j)
                    acc[i][j] += a[i] * b[j];
        }
    }

    #pragma unroll
    for (int i = 0; i < 4; ++i) {
        int row = rowBase + ty * 4 + i;
        #pragma unroll
        for (int j = 0; j < 4; ++j) {
            int col = colBase + tx * 4 + j;
            float v = acc[i][j] + bias[col];
            if (scatter) {
                // row = b*L + l ; col = h*DK + d  ->  [B,H,L,DK]
                int b_ = row >> 10, l_ = row & 1023;
                int h_ = col >> 6,  d_ = col & 63;
                size_t idx = ((size_t)(b_ * NHEAD + h_) * LSEQ + l_) * DKD + d_;
                C[idx] = v;
            } else {
                size_t idx = (size_t)row * N + col;
                if (resid) v += resid[idx];
                if (relu)  v = fmaxf(v, 0.f);
                C[idx] = v;
            }
        }
    }
}

// ---------------------------------------------------------------------------
// Flash-style biased attention. One block = 32 query rows of one (b,h).
// 4 waves x 8 rows. lane = key index (QK) / dim index (PV). DK = 64.
// out written in [B, L, H*DK] layout (ready for the out-projection GEMM).
// ---------------------------------------------------------------------------
__global__ __launch_bounds__(256) void attn_kernel(
    const float* __restrict__ Qg, const float* __restrict__ Kg,
    const float* __restrict__ Vg, const float* __restrict__ bias,
    const unsigned char* __restrict__ mask, float* __restrict__ out)
{
    __shared__ float Qs[32][68];
    __shared__ float Ks[64][68];
    __shared__ float Vs[64][68];
    __shared__ float Ps[4][8][64];

    const int t    = threadIdx.x;
    const int lane = t & 63;
    const int w    = t >> 6;
    const int blk  = blockIdx.x;          // B*H*(L/32) = 2048
    const int qt   = blk & 31;
    const int bh   = blk >> 5;            // 0..63
    const int b_   = bh >> 3;
    const int h_   = bh & 7;
    const int qrow0 = qt * 32;
    const size_t bhBase = (size_t)bh * LSEQ * DKD;

    {   // stage Q tile (32x64)
        int r = t >> 3, c8 = (t & 7) * 8;
        const float* src = Qg + bhBase + (size_t)(qrow0 + r) * DKD + c8;
        *(float4*)&Qs[r][c8]     = *(const float4*)(src);
        *(float4*)&Qs[r][c8 + 4] = *(const float4*)(src + 4);
    }

    const int wr0 = w * 8;
    float m[8], l[8], o[8];
    #pragma unroll
    for (int r = 0; r < 8; ++r) { m[r] = -1e30f; l[r] = 0.f; o[r] = 0.f; }

    const float* biasRow = bias + (size_t)b_ * LSEQ * LSEQ + (size_t)(qrow0 + wr0) * LSEQ;
    const unsigned char* maskRow = mask + (size_t)b_ * LSEQ;

    for (int kt = 0; kt < 16; ++kt) {
        const int key0 = kt * 64;
        __syncthreads();   // prev PV done (and Q staged on first pass)
        {   // stage K,V tiles (64x64 each)
            int r = t >> 2, c = (t & 3) * 16;
            const float* ksrc = Kg + bhBase + (size_t)(key0 + r) * DKD + c;
            const float* vsrc = Vg + bhBase + (size_t)(key0 + r) * DKD + c;
            #pragma unroll
            for (int i = 0; i < 4; ++i) {
                *(float4*)&Ks[r][c + i * 4] = *(const float4*)(ksrc + i * 4);
                *(float4*)&Vs[r][c + i * 4] = *(const float4*)(vsrc + i * 4);
            }
        }
        __syncthreads();

        // S = Q K^T : lane handles key (key0+lane) for all 8 rows
        float s[8] = {0, 0, 0, 0, 0, 0, 0, 0};
        #pragma unroll
        for (int d0 = 0; d0 < 16; ++d0) {
            float4 k4 = *(const float4*)&Ks[lane][d0 * 4];
            #pragma unroll
            for (int r = 0; r < 8; ++r) {
                float4 q4 = *(const float4*)&Qs[wr0 + r][d0 * 4];
                s[r] += k4.x * q4.x + k4.y * q4.y + k4.z * q4.z + k4.w * q4.w;
            }
        }

        const unsigned char mk = maskRow[key0 + lane];
        float osc[8];
        #pragma unroll
        for (int r = 0; r < 8; ++r) {
            float sv = s[r] * 0.125f + biasRow[(size_t)r * LSEQ + key0 + lane];
            if (mk) sv = -1e30f;
            float mt = sv;
            #pragma unroll
            for (int off = 32; off; off >>= 1) mt = fmaxf(mt, __shfl_xor(mt, off));
            float mn = fmaxf(m[r], mt);
            float p  = __expf(sv - mn);
            float sc = __expf(m[r] - mn);
            float ps = p;
            #pragma unroll
            for (int off = 32; off; off >>= 1) ps += __shfl_xor(ps, off);
            l[r] = l[r] * sc + ps;
            m[r] = mn;
            osc[r] = sc;
            Ps[w][r][lane] = p;
        }
        __syncthreads();   // P visible across lanes

        #pragma unroll
        for (int r = 0; r < 8; ++r) o[r] *= osc[r];
        #pragma unroll
        for (int j0 = 0; j0 < 16; ++j0) {
            float v0 = Vs[j0 * 4 + 0][lane];
            float v1 = Vs[j0 * 4 + 1][lane];
            float v2 = Vs[j0 * 4 + 2][lane];
            float v3 = Vs[j0 * 4 + 3][lane];
            #pragma unroll
            for (int r = 0; r < 8; ++r) {
                float4 p4 = *(const float4*)&Ps[w][r][j0 * 4];
                o[r] += p4.x * v0 + p4.y * v1 + p4.z * v2 + p4.w * v3;
            }
        }
    }

    #pragma unroll
    for (int r = 0; r < 8; ++r) {
        float val = o[r] / l[r];
        out[(size_t)(b_ * LSEQ + qrow0 + wr0 + r) * DMODEL + h_ * DKD + lane] = val;
    }
}

// ---------------------------------------------------------------------------
// LayerNorm over last dim (512). One wave per row, 8 floats per lane.
// Safe in-place (row fully loaded before any store).
// ---------------------------------------------------------------------------
__global__ __launch_bounds__(256) void ln_kernel(
    const float* __restrict__ in, const float* __restrict__ g,
    const float* __restrict__ bt, float* __restrict__ out)
{
    const int row  = blockIdx.x * 4 + (threadIdx.x >> 6);
    const int lane = threadIdx.x & 63;
    const float* rp = in + (size_t)row * DMODEL + lane * 8;
    float4 x0 = *(const float4*)rp;
    float4 x1 = *(const float4*)(rp + 4);
    float xs[8] = {x0.x, x0.y, x0.z, x0.w, x1.x, x1.y, x1.z, x1.w};

    float sum = 0.f;
    #pragma unroll
    for (int i = 0; i < 8; ++i) sum += xs[i];
    #pragma unroll
    for (int off = 32; off; off >>= 1) sum += __shfl_xor(sum, off);
    float mu = sum * (1.f / 512.f);

    float vs = 0.f;
    #pragma unroll
    for (int i = 0; i < 8; ++i) { float d = xs[i] - mu; vs += d * d; }
    #pragma unroll
    for (int off = 32; off; off >>= 1) vs += __shfl_xor(vs, off);
    float rs = rsqrtf(vs * (1.f / 512.f) + 1e-5f);

    const float* gp = g  + lane * 8;
    const float* bp = bt + lane * 8;
    float4 g0 = *(const float4*)gp,        g1 = *(const float4*)(gp + 4);
    float4 b0 = *(const float4*)bp,        b1 = *(const float4*)(bp + 4);
    float gs[8] = {g0.x, g0.y, g0.z, g0.w, g1.x, g1.y, g1.z, g1.w};
    float bs[8] = {b0.x, b0.y, b0.z, b0.w, b1.x, b1.y, b1.z, b1.w};

    float* op = out + (size_t)row * DMODEL + lane * 8;
    float res[8];
    #pragma unroll
    for (int i = 0; i < 8; ++i) res[i] = (xs[i] - mu) * rs * gs[i] + bs[i];
    float4 r0 = {res[0], res[1], res[2], res[3]};
    float4 r1 = {res[4], res[5], res[6], res[7]};
    *(float4*)op       = r0;
    *(float4*)(op + 4) = r1;
}

// ---------------------------------------------------------------------------
extern "C" void kernel_launch(void* const* d_in, const int* in_sizes, int n_in,
                              void* d_out, int out_size, void* d_ws, size_t ws_size,
                              hipStream_t stream)
{
    const float*         x    = (const float*)d_in[0];
    const unsigned char* mask = (const unsigned char*)d_in[1];
    const float*         bias = (const float*)d_in[2];
    const float* Wq = (const float*)d_in[3];
    const float* bq = (const float*)d_in[4];
    const float* Wk = (const float*)d_in[5];
    const float* bk = (const float*)d_in[6];
    const float* Wv = (const float*)d_in[7];
    const float* bv = (const float*)d_in[8];
    const float* Wo = (const float*)d_in[9];
    const float* bo = (const float*)d_in[10];
    const float* ln1g = (const float*)d_in[11];
    const float* ln1b = (const float*)d_in[12];
    const float* W1 = (const float*)d_in[13];
    const float* b1 = (const float*)d_in[14];
    const float* W2 = (const float*)d_in[15];
    const float* b2 = (const float*)d_in[16];
    const float* ln2g = (const float*)d_in[17];
    const float* ln2b = (const float*)d_in[18];

    float* ws = (float*)d_ws;
    float* qb   = ws;                 // [B,H,L,DK]   16 MiB floats each
    float* kb   = ws + 4194304;
    float* vb   = ws + 8388608;
    float* ab   = ws + 12582912;      // attn out, [BL, 512]
    float* hb   = ws;                 // FFN hidden [BL,2048] — reuses q/k/v/ab (dead)
    float* x1   = ws + 16777216;      // post-LN1 activations (residual for block 2)
    float* y2   = ws + 20971520;      // pre-LN2
    float* outp = (float*)d_out;

    dim3 blk(256);
    dim3 g512(512 / 64, NBL / 64);
    dim3 g2048(2048 / 64, NBL / 64);

    // QKV projections (scatter into [B,H,L,DK])
    gemm_kernel<<<g512, blk, 0, stream>>>(x, Wq, bq, nullptr, qb, NBL, 512, 512, 0, 1);
    gemm_kernel<<<g512, blk, 0, stream>>>(x, Wk, bk, nullptr, kb, NBL, 512, 512, 0, 1);
    gemm_kernel<<<g512, blk, 0, stream>>>(x, Wv, bv, nullptr, vb, NBL, 512, 512, 0, 1);

    // Attention
    attn_kernel<<<dim3(2048), blk, 0, stream>>>(qb, kb, vb, bias, mask, ab);

    // Out projection + residual(x) -> x1 buffer, then LN1 in-place
    gemm_kernel<<<g512, blk, 0, stream>>>(ab, Wo, bo, x, x1, NBL, 512, 512, 0, 0);
    ln_kernel<<<dim3(NBL / 4), blk, 0, stream>>>(x1, ln1g, ln1b, x1);

    // FFN
    gemm_kernel<<<g2048, blk, 0, stream>>>(x1, W1, b1, nullptr, hb, NBL, 2048, 512, 1, 0);
    gemm_kernel<<<g512, blk, 0, stream>>>(hb, W2, b2, x1, y2, NBL, 512, 2048, 0, 0);

    // LN2 -> final output
    ln_kernel<<<dim3(NBL / 4), blk, 0, stream>>>(y2, ln2g, ln2b, outp);
}

// Round 4
// 435.874 us; speedup vs baseline: 4.0963x; 4.0963x over previous
//
#include <hip/hip_runtime.h>
#include <math.h>

#define NHEAD 8
#define DKD 64
#define DMODEL 512
#define LSEQ 1024
#define NBL 8192          // B*L

typedef __attribute__((ext_vector_type(8))) short bf8;   // 8 x bf16 (4 VGPRs)
typedef __attribute__((ext_vector_type(4))) float f4;    // MFMA accumulator

__device__ inline unsigned short f2bf(float f) {
    union { float f; unsigned u; } v; v.f = f;
    unsigned r = v.u + 0x7FFFu + ((v.u >> 16) & 1u);   // RNE
    return (unsigned short)(r >> 16);
}

// ---------------------------------------------------------------------------
// prepass: fp32 -> bf16 elementwise
// ---------------------------------------------------------------------------
__global__ __launch_bounds__(256) void conv_bf16(
    const float* __restrict__ in, unsigned short* __restrict__ out, int n)
{
    int i = (blockIdx.x * 256 + threadIdx.x) * 4;
    if (i >= n) return;
    float4 v = *(const float4*)(in + i);
    ushort4 o;
    o.x = f2bf(v.x); o.y = f2bf(v.y); o.z = f2bf(v.z); o.w = f2bf(v.w);
    *(ushort4*)(out + i) = o;
}

// ---------------------------------------------------------------------------
// prepass: W[K,N] fp32 -> Wt[N,K] bf16 (LDS-tiled transpose, both sides coalesced)
// ---------------------------------------------------------------------------
__global__ __launch_bounds__(256) void transpose_bf16(
    const float* __restrict__ W, unsigned short* __restrict__ Wt, int K, int N)
{
    __shared__ float tile[64][65];
    const int k0 = blockIdx.y * 64, n0 = blockIdx.x * 64;
    const int c = threadIdx.x & 63, r0 = (threadIdx.x >> 6) * 16;
    #pragma unroll
    for (int i = 0; i < 16; ++i)
        tile[r0 + i][c] = W[(size_t)(k0 + r0 + i) * N + n0 + c];
    __syncthreads();
    #pragma unroll
    for (int i = 0; i < 16; ++i)
        Wt[(size_t)(n0 + r0 + i) * K + k0 + c] = f2bf(tile[c][r0 + i]);
}

__global__ void concat3(const float* __restrict__ a, const float* __restrict__ b,
                        const float* __restrict__ c, float* __restrict__ o)
{
    int i = blockIdx.x * 256 + threadIdx.x;
    if (i < 512) o[i] = a[i];
    else if (i < 1024) o[i] = b[i - 512];
    else if (i < 1536) o[i] = c[i - 1024];
}

// ---------------------------------------------------------------------------
// bf16 MFMA GEMM: C[M,N] = A[M,K] @ Bt[N,K]^T + bias
// 128x128 tile, 4 waves (2x2), BK=64, XOR-swizzled LDS (T2).
// outmode: 0 = fp32 [M,N] (+resid), 1 = bf16 [M,N] (+relu), 2 = QKV scatter bf16
// ---------------------------------------------------------------------------
__global__ __launch_bounds__(256) void mfma_gemm(
    const unsigned short* __restrict__ A, const unsigned short* __restrict__ Bt,
    const float* __restrict__ bias, const float* __restrict__ resid,
    void* __restrict__ outp, int M, int N, int K, int relu, int outmode,
    unsigned short* __restrict__ qs, unsigned short* __restrict__ ks,
    unsigned short* __restrict__ vts)
{
    __shared__ uint4 As[1024];   // [128 rows][8 chunks of 16B], chunk ^= row&7
    __shared__ uint4 Bs[1024];

    const int t = threadIdx.x;
    const int lane = t & 63, w = t >> 6;
    const int g = lane >> 4, r15 = lane & 15;
    const int wr = w >> 1, wc = w & 1;
    const int rowBase = blockIdx.y * 128, colBase = blockIdx.x * 128;

    f4 acc[4][4] = {};

    for (int k0 = 0; k0 < K; k0 += 64) {
        __syncthreads();
        #pragma unroll
        for (int i = 0; i < 4; ++i) {
            int linear = i * 256 + t;
            int row = linear >> 3, ch = linear & 7;
            As[row * 8 + (ch ^ (row & 7))] =
                *(const uint4*)(A + (size_t)(rowBase + row) * K + k0 + ch * 8);
            Bs[row * 8 + (ch ^ (row & 7))] =
                *(const uint4*)(Bt + (size_t)(colBase + row) * K + k0 + ch * 8);
        }
        __syncthreads();
        #pragma unroll
        for (int kk = 0; kk < 2; ++kk) {
            bf8 af[4], bfr[4];
            #pragma unroll
            for (int m = 0; m < 4; ++m) {
                int ra = wr * 64 + m * 16 + r15;
                af[m] = *(const bf8*)&As[ra * 8 + ((kk * 4 + g) ^ (ra & 7))];
                int rb = wc * 64 + m * 16 + r15;
                bfr[m] = *(const bf8*)&Bs[rb * 8 + ((kk * 4 + g) ^ (rb & 7))];
            }
            #pragma unroll
            for (int m = 0; m < 4; ++m)
                #pragma unroll
                for (int n = 0; n < 4; ++n)
                    acc[m][n] = __builtin_amdgcn_mfma_f32_16x16x32_bf16(
                        af[m], bfr[n], acc[m][n], 0, 0, 0);
        }
    }

    #pragma unroll
    for (int m = 0; m < 4; ++m) {
        #pragma unroll
        for (int n = 0; n < 4; ++n) {
            int col = colBase + wc * 64 + n * 16 + r15;
            float bv = bias[col];
            #pragma unroll
            for (int r = 0; r < 4; ++r) {
                int row = rowBase + wr * 64 + m * 16 + g * 4 + r;
                float v = acc[m][n][r] + bv;
                if (relu) v = fmaxf(v, 0.f);
                if (outmode == 0) {
                    size_t idx = (size_t)row * N + col;
                    if (resid) v += resid[idx];
                    ((float*)outp)[idx] = v;
                } else if (outmode == 1) {
                    ((unsigned short*)outp)[(size_t)row * N + col] = f2bf(v);
                } else {
                    int sel = col >> 9, hd = col & 511;
                    int h = hd >> 6, dk = hd & 63;
                    int b = row >> 10, l = row & 1023;
                    unsigned short bw = f2bf(v);
                    size_t bh = (size_t)(b * NHEAD + h);
                    if (sel == 0)      qs[(bh * LSEQ + l) * DKD + dk] = bw;
                    else if (sel == 1) ks[(bh * LSEQ + l) * DKD + dk] = bw;
                    else               vts[(bh * DKD + dk) * LSEQ + l] = bw;
                }
            }
        }
    }
}

// ---------------------------------------------------------------------------
// Flash attention, bf16 MFMA. Block = 64 q-rows of one (b,h); 4 waves x 16 rows.
// Q stationary in regs; K / V^T tiles in swizzled LDS; softmax fp32 in regs;
// P transposed to A-fragment layout via per-wave padded LDS buffer.
// ---------------------------------------------------------------------------
__global__ __launch_bounds__(256) void attn_mfma(
    const unsigned short* __restrict__ Qg, const unsigned short* __restrict__ Kg,
    const unsigned short* __restrict__ Vtg, const float* __restrict__ bias,
    const unsigned char* __restrict__ mask, unsigned short* __restrict__ Ob)
{
    __shared__ uint4 Ks[512];            // [64 keys][8 chunks], swizzled
    __shared__ uint4 Vs[512];            // [64 dk][8 chunks of keys], swizzled
    __shared__ float Ps[4][16][68];      // per-wave P scratch (fp32, padded)

    const int t = threadIdx.x;
    const int lane = t & 63, w = t >> 6;
    const int g = lane >> 4, r15 = lane & 15;

    // XCD-aware remap: 8 consecutive bh per XCD (K/V L2 locality)
    const int p = blockIdx.x;
    const int logical = (p & 7) * 128 + (p >> 3);
    const int bh = logical >> 4, qt = logical & 15;
    const int b = bh >> 3, h = bh & 7;

    bf8 qf[2];
    {
        int qrow = qt * 64 + w * 16 + r15;
        const unsigned short* qp = Qg + ((size_t)bh * LSEQ + qrow) * DKD + g * 8;
        qf[0] = *(const bf8*)qp;
        qf[1] = *(const bf8*)(qp + 32);
    }

    float mrun[4], lsum[4];
    f4 oacc[4] = {};
    #pragma unroll
    for (int r = 0; r < 4; ++r) { mrun[r] = -1e30f; lsum[r] = 0.f; }

    const float* biasBase = bias + ((size_t)b << 20) + (size_t)(qt * 64 + w * 16 + g * 4) * LSEQ;
    const unsigned char* maskB = mask + b * LSEQ;

    for (int kt = 0; kt < 16; ++kt) {
        const int key0 = kt * 64;
        __syncthreads();
        #pragma unroll
        for (int i = 0; i < 2; ++i) {
            int linear = i * 256 + t;
            int row = linear >> 3, ch = linear & 7;
            Ks[row * 8 + (ch ^ (row & 7))] =
                *(const uint4*)(Kg + ((size_t)bh * LSEQ + key0 + row) * DKD + ch * 8);
            Vs[row * 8 + (ch ^ (row & 7))] =
                *(const uint4*)(Vtg + ((size_t)bh * DKD + row) * LSEQ + key0 + ch * 8);
        }
        __syncthreads();

        // S = Q K^T  (C: row = local q = g*4+reg, col = key = n*16 + r15)
        f4 sacc[4] = {};
        #pragma unroll
        for (int kk = 0; kk < 2; ++kk)
            #pragma unroll
            for (int n = 0; n < 4; ++n) {
                int row = n * 16 + r15;
                bf8 kf = *(const bf8*)&Ks[row * 8 + ((kk * 4 + g) ^ (row & 7))];
                sacc[n] = __builtin_amdgcn_mfma_f32_16x16x32_bf16(qf[kk], kf, sacc[n], 0, 0, 0);
            }

        // softmax (fp32, online)
        float pv[4][4], mt[4] = {-1e30f, -1e30f, -1e30f, -1e30f};
        #pragma unroll
        for (int n = 0; n < 4; ++n) {
            unsigned char mk = maskB[key0 + n * 16 + r15];
            #pragma unroll
            for (int r = 0; r < 4; ++r) {
                float s = sacc[n][r] * 0.125f + biasBase[(size_t)r * LSEQ + key0 + n * 16 + r15];
                if (mk) s = -1e30f;
                pv[n][r] = s;
                mt[r] = fmaxf(mt[r], s);
            }
        }
        #pragma unroll
        for (int r = 0; r < 4; ++r) {
            #pragma unroll
            for (int off = 1; off < 16; off <<= 1)
                mt[r] = fmaxf(mt[r], __shfl_xor(mt[r], off));
        }
        float sc[4], ps[4];
        #pragma unroll
        for (int r = 0; r < 4; ++r) {
            float mn = fmaxf(mrun[r], mt[r]);
            sc[r] = __expf(mrun[r] - mn);
            mrun[r] = mn;
            ps[r] = 0.f;
        }
        #pragma unroll
        for (int n = 0; n < 4; ++n)
            #pragma unroll
            for (int r = 0; r < 4; ++r) {
                pv[n][r] = __expf(pv[n][r] - mrun[r]);
                ps[r] += pv[n][r];
            }
        #pragma unroll
        for (int r = 0; r < 4; ++r) {
            #pragma unroll
            for (int off = 1; off < 16; off <<= 1) ps[r] += __shfl_xor(ps[r], off);
            lsum[r] = lsum[r] * sc[r] + ps[r];
        }
        #pragma unroll
        for (int nd = 0; nd < 4; ++nd)
            #pragma unroll
            for (int r = 0; r < 4; ++r) oacc[nd][r] *= sc[r];

        // P -> per-wave LDS (fp32), then read back in A-fragment layout
        #pragma unroll
        for (int n = 0; n < 4; ++n)
            #pragma unroll
            for (int r = 0; r < 4; ++r)
                Ps[w][g * 4 + r][n * 16 + r15] = pv[n][r];

        #pragma unroll
        for (int kk = 0; kk < 2; ++kk) {
            const float* pp = &Ps[w][r15][kk * 32 + g * 8];
            bf8 af;
            #pragma unroll
            for (int i = 0; i < 8; ++i) af[i] = (short)f2bf(pp[i]);
            #pragma unroll
            for (int nd = 0; nd < 4; ++nd) {
                int row = nd * 16 + r15;
                bf8 vf = *(const bf8*)&Vs[row * 8 + ((kk * 4 + g) ^ (row & 7))];
                oacc[nd] = __builtin_amdgcn_mfma_f32_16x16x32_bf16(af, vf, oacc[nd], 0, 0, 0);
            }
        }
    }

    #pragma unroll
    for (int r = 0; r < 4; ++r) {
        float inv = 1.f / lsum[r];
        int qrow = qt * 64 + w * 16 + g * 4 + r;
        unsigned short* op = Ob + ((size_t)b * LSEQ + qrow) * DMODEL + h * DKD + r15;
        #pragma unroll
        for (int nd = 0; nd < 4; ++nd)
            op[nd * 16] = f2bf(oacc[nd][r] * inv);
    }
}

// ---------------------------------------------------------------------------
// LayerNorm (fp32), optional bf16 secondary output. One wave per row of 512.
// ---------------------------------------------------------------------------
__global__ __launch_bounds__(256) void ln_kernel(
    const float* __restrict__ in, const float* __restrict__ g,
    const float* __restrict__ bt, float* __restrict__ out,
    unsigned short* __restrict__ outb)
{
    const int row  = blockIdx.x * 4 + (threadIdx.x >> 6);
    const int lane = threadIdx.x & 63;
    const float* rp = in + (size_t)row * DMODEL + lane * 8;
    float4 x0 = *(const float4*)rp;
    float4 x1 = *(const float4*)(rp + 4);
    float xs[8] = {x0.x, x0.y, x0.z, x0.w, x1.x, x1.y, x1.z, x1.w};

    float sum = 0.f;
    #pragma unroll
    for (int i = 0; i < 8; ++i) sum += xs[i];
    #pragma unroll
    for (int off = 32; off; off >>= 1) sum += __shfl_xor(sum, off);
    float mu = sum * (1.f / 512.f);

    float vs = 0.f;
    #pragma unroll
    for (int i = 0; i < 8; ++i) { float d = xs[i] - mu; vs += d * d; }
    #pragma unroll
    for (int off = 32; off; off >>= 1) vs += __shfl_xor(vs, off);
    float rs = rsqrtf(vs * (1.f / 512.f) + 1e-5f);

    const float* gp = g  + lane * 8;
    const float* bp = bt + lane * 8;
    float4 g0 = *(const float4*)gp, g1 = *(const float4*)(gp + 4);
    float4 b0 = *(const float4*)bp, b1 = *(const float4*)(bp + 4);
    float gs[8] = {g0.x, g0.y, g0.z, g0.w, g1.x, g1.y, g1.z, g1.w};
    float bs[8] = {b0.x, b0.y, b0.z, b0.w, b1.x, b1.y, b1.z, b1.w};

    float res[8];
    #pragma unroll
    for (int i = 0; i < 8; ++i) res[i] = (xs[i] - mu) * rs * gs[i] + bs[i];

    float* op = out + (size_t)row * DMODEL + lane * 8;
    float4 r0 = {res[0], res[1], res[2], res[3]};
    float4 r1 = {res[4], res[5], res[6], res[7]};
    *(float4*)op       = r0;
    *(float4*)(op + 4) = r1;

    if (outb) {
        unsigned short* ob = outb + (size_t)row * DMODEL + lane * 8;
        ushort4 u0, u1;
        u0.x = f2bf(res[0]); u0.y = f2bf(res[1]); u0.z = f2bf(res[2]); u0.w = f2bf(res[3]);
        u1.x = f2bf(res[4]); u1.y = f2bf(res[5]); u1.z = f2bf(res[6]); u1.w = f2bf(res[7]);
        *(ushort4*)ob       = u0;
        *(ushort4*)(ob + 4) = u1;
    }
}

// ---------------------------------------------------------------------------
extern "C" void kernel_launch(void* const* d_in, const int* in_sizes, int n_in,
                              void* d_out, int out_size, void* d_ws, size_t ws_size,
                              hipStream_t stream)
{
    const float*         x    = (const float*)d_in[0];
    const unsigned char* mask = (const unsigned char*)d_in[1];
    const float*         bias = (const float*)d_in[2];
    const float* Wq = (const float*)d_in[3];
    const float* bq = (const float*)d_in[4];
    const float* Wk = (const float*)d_in[5];
    const float* bk = (const float*)d_in[6];
    const float* Wv = (const float*)d_in[7];
    const float* bv = (const float*)d_in[8];
    const float* Wo = (const float*)d_in[9];
    const float* bo = (const float*)d_in[10];
    const float* ln1g = (const float*)d_in[11];
    const float* ln1b = (const float*)d_in[12];
    const float* W1 = (const float*)d_in[13];
    const float* b1 = (const float*)d_in[14];
    const float* W2 = (const float*)d_in[15];
    const float* b2 = (const float*)d_in[16];
    const float* ln2g = (const float*)d_in[17];
    const float* ln2b = (const float*)d_in[18];

    char* W = (char*)d_ws;
    unsigned short* Qb   = (unsigned short*)(W);                       // 8 MB
    unsigned short* Kb   = (unsigned short*)(W + (8u << 20));          // 8 MB
    unsigned short* Vtb  = (unsigned short*)(W + (16u << 20));         // 8 MB
    unsigned short* Oball= (unsigned short*)(W + (24u << 20));         // 8 MB
    unsigned short* hb   = (unsigned short*)(W);                       // 32 MB (reuses Q/K/Vt/O)
    float*          y12  = (float*)(W + (32u << 20));                  // 16 MB (y1 then y2)
    float*          x1   = (float*)(W + (48u << 20));                  // 16 MB
    unsigned short* xb   = (unsigned short*)(W + (64u << 20));         // 8 MB
    unsigned short* x1b  = xb;                                         // reuse after GEMM1
    unsigned short* Wqkv = (unsigned short*)(W + (72u << 20));         // 1.5 MB
    unsigned short* Wot  = (unsigned short*)(W + (74u << 20));         // 0.5 MB
    unsigned short* W1t  = (unsigned short*)(W + (75u << 20));         // 2 MB
    unsigned short* W2t  = (unsigned short*)(W + (77u << 20));         // 2 MB
    float*          bqkv = (float*)(W + (79u << 20));                  // 6 KB
    float*          outp = (float*)d_out;

    // prepass
    conv_bf16<<<dim3(4096), dim3(256), 0, stream>>>(x, xb, NBL * DMODEL);
    transpose_bf16<<<dim3(8, 8),  dim3(256), 0, stream>>>(Wq, Wqkv,          512, 512);
    transpose_bf16<<<dim3(8, 8),  dim3(256), 0, stream>>>(Wk, Wqkv + 262144, 512, 512);
    transpose_bf16<<<dim3(8, 8),  dim3(256), 0, stream>>>(Wv, Wqkv + 524288, 512, 512);
    transpose_bf16<<<dim3(8, 8),  dim3(256), 0, stream>>>(Wo, Wot, 512, 512);
    transpose_bf16<<<dim3(32, 8), dim3(256), 0, stream>>>(W1, W1t, 512, 2048);
    transpose_bf16<<<dim3(8, 32), dim3(256), 0, stream>>>(W2, W2t, 2048, 512);
    concat3<<<dim3(6), dim3(256), 0, stream>>>(bq, bk, bv, bqkv);

    // QKV fused projection, scatter to Q/K [bh,l,dk] and V^T [bh,dk,l]
    mfma_gemm<<<dim3(12, 64), dim3(256), 0, stream>>>(
        xb, Wqkv, bqkv, nullptr, nullptr, NBL, 1536, 512, 0, 2, Qb, Kb, Vtb);

    // attention
    attn_mfma<<<dim3(1024), dim3(256), 0, stream>>>(Qb, Kb, Vtb, bias, mask, Oball);

    // out projection + residual(x) -> y1 (fp32)
    mfma_gemm<<<dim3(4, 64), dim3(256), 0, stream>>>(
        Oball, Wot, bo, x, y12, NBL, 512, 512, 0, 0, nullptr, nullptr, nullptr);

    // LN1 -> x1 (fp32) + x1b (bf16)
    ln_kernel<<<dim3(NBL / 4), dim3(256), 0, stream>>>(y12, ln1g, ln1b, x1, x1b);

    // FFN1: relu(x1 @ W1 + b1) -> hb (bf16)
    mfma_gemm<<<dim3(16, 64), dim3(256), 0, stream>>>(
        x1b, W1t, b1, nullptr, hb, NBL, 2048, 512, 1, 1, nullptr, nullptr, nullptr);

    // FFN2: hb @ W2 + b2 + x1 -> y2 (fp32)
    mfma_gemm<<<dim3(4, 64), dim3(256), 0, stream>>>(
        hb, W2t, b2, x1, y12, NBL, 512, 2048, 0, 0, nullptr, nullptr, nullptr);

    // LN2 -> output
    ln_kernel<<<dim3(NBL / 4), dim3(256), 0, stream>>>(y12, ln2g, ln2b, outp, nullptr);
}

// Round 5
// 386.686 us; speedup vs baseline: 4.6173x; 1.1272x over previous
//
#include <hip/hip_runtime.h>
#include <math.h>

#define NHEAD 8
#define DKD 64
#define DMODEL 512
#define LSEQ 1024
#define NBL 8192          // B*L

typedef __attribute__((ext_vector_type(8))) short bf8;   // 8 x bf16 (4 VGPRs)
typedef __attribute__((ext_vector_type(4))) float f4;    // MFMA accumulator

__device__ inline unsigned short f2bf(float f) {
    union { float f; unsigned u; } v; v.f = f;
    unsigned r = v.u + 0x7FFFu + ((v.u >> 16) & 1u);   // RNE
    return (unsigned short)(r >> 16);
}

// async global->LDS, 16B per lane. LDS dest = wave-uniform base + lane*16.
__device__ __forceinline__ void gload16(const void* g, void* l) {
    __builtin_amdgcn_global_load_lds(
        (const __attribute__((address_space(1))) unsigned int*)g,
        (__attribute__((address_space(3))) unsigned int*)l, 16, 0, 0);
}

// ---------------------------------------------------------------------------
// prepass kernels
// ---------------------------------------------------------------------------
__global__ __launch_bounds__(256) void conv_bf16(
    const float* __restrict__ in, unsigned short* __restrict__ out, int n)
{
    int i = (blockIdx.x * 256 + threadIdx.x) * 4;
    if (i >= n) return;
    float4 v = *(const float4*)(in + i);
    ushort4 o;
    o.x = f2bf(v.x); o.y = f2bf(v.y); o.z = f2bf(v.z); o.w = f2bf(v.w);
    *(ushort4*)(out + i) = o;
}

__global__ __launch_bounds__(256) void transpose_bf16(
    const float* __restrict__ W, unsigned short* __restrict__ Wt, int K, int N)
{
    __shared__ float tile[64][65];
    const int k0 = blockIdx.y * 64, n0 = blockIdx.x * 64;
    const int c = threadIdx.x & 63, r0 = (threadIdx.x >> 6) * 16;
    #pragma unroll
    for (int i = 0; i < 16; ++i)
        tile[r0 + i][c] = W[(size_t)(k0 + r0 + i) * N + n0 + c];
    __syncthreads();
    #pragma unroll
    for (int i = 0; i < 16; ++i)
        Wt[(size_t)(n0 + r0 + i) * K + k0 + c] = f2bf(tile[c][r0 + i]);
}

__global__ void concat3(const float* __restrict__ a, const float* __restrict__ b,
                        const float* __restrict__ c, float* __restrict__ o)
{
    int i = blockIdx.x * 256 + threadIdx.x;
    if (i < 512) o[i] = a[i];
    else if (i < 1024) o[i] = b[i - 512];
    else if (i < 1536) o[i] = c[i - 1024];
}

__global__ void maskf_kernel(const unsigned char* __restrict__ m,
                             float* __restrict__ o, int n)
{
    int i = blockIdx.x * 256 + threadIdx.x;
    if (i < n) o[i] = m[i] ? -1e30f : 0.f;
}

// ---------------------------------------------------------------------------
// bf16 MFMA GEMM: C[M,N] = A[M,K] @ Bt[N,K]^T + bias
// 128x128 tile, 4 waves (2x2), BK=64. Staging: global_load_lds width=16 with
// PRE-SWIZZLED global source chunk (chunk ^= row&7) -> LDS linear, reads use
// the same XOR -> conflict-free ds_read_b128 (m173/s09 pattern).
// outmode: 0 = fp32 [M,N] (+resid), 1 = bf16 [M,N] (+relu), 2 = QKV scatter bf16
// ---------------------------------------------------------------------------
__global__ __launch_bounds__(256) void mfma_gemm(
    const unsigned short* __restrict__ A, const unsigned short* __restrict__ Bt,
    const float* __restrict__ bias, const float* __restrict__ resid,
    void* __restrict__ outp, int M, int N, int K, int relu, int outmode,
    unsigned short* __restrict__ qs, unsigned short* __restrict__ ks,
    unsigned short* __restrict__ vts)
{
    __shared__ uint4 As[1024];   // [128 rows][8 chunks of 16B] (linear)
    __shared__ uint4 Bs[1024];

    const int t = threadIdx.x;
    const int lane = t & 63, w = t >> 6;
    const int g = lane >> 4, r15 = lane & 15;
    const int wr = w >> 1, wc = w & 1;
    const int rowBase = blockIdx.y * 128, colBase = blockIdx.x * 128;

    f4 acc[4][4] = {};

    const int r  = t >> 3;                    // 0..31 (wave w owns rows w*8..w*8+7)
    const int chs = (t & 7) ^ (r & 7);        // pre-swizzled source chunk
    unsigned short* Al = (unsigned short*)As + (w * 8) * 64;   // wave-uniform
    unsigned short* Bl = (unsigned short*)Bs + (w * 8) * 64;

    for (int k0 = 0; k0 < K; k0 += 64) {
        __syncthreads();
        {
            const unsigned short* Ag = A  + (size_t)(rowBase + r) * K + k0 + chs * 8;
            const unsigned short* Bg = Bt + (size_t)(colBase + r) * K + k0 + chs * 8;
            #pragma unroll
            for (int p = 0; p < 4; ++p) {
                gload16(Ag + (size_t)(p * 32) * K, Al + p * 32 * 64);
                gload16(Bg + (size_t)(p * 32) * K, Bl + p * 32 * 64);
            }
        }
        __syncthreads();   // drains vmcnt before use
        #pragma unroll
        for (int kk = 0; kk < 2; ++kk) {
            bf8 af[4], bfr[4];
            #pragma unroll
            for (int m = 0; m < 4; ++m) {
                int ra = wr * 64 + m * 16 + r15;
                af[m] = *(const bf8*)&As[ra * 8 + ((kk * 4 + g) ^ (ra & 7))];
                int rb = wc * 64 + m * 16 + r15;
                bfr[m] = *(const bf8*)&Bs[rb * 8 + ((kk * 4 + g) ^ (rb & 7))];
            }
            #pragma unroll
            for (int m = 0; m < 4; ++m)
                #pragma unroll
                for (int n = 0; n < 4; ++n)
                    acc[m][n] = __builtin_amdgcn_mfma_f32_16x16x32_bf16(
                        af[m], bfr[n], acc[m][n], 0, 0, 0);
        }
    }

    #pragma unroll
    for (int m = 0; m < 4; ++m) {
        #pragma unroll
        for (int n = 0; n < 4; ++n) {
            int col = colBase + wc * 64 + n * 16 + r15;
            float bv = bias[col];
            #pragma unroll
            for (int rr = 0; rr < 4; ++rr) {
                int row = rowBase + wr * 64 + m * 16 + g * 4 + rr;
                float v = acc[m][n][rr] + bv;
                if (relu) v = fmaxf(v, 0.f);
                if (outmode == 0) {
                    size_t idx = (size_t)row * N + col;
                    if (resid) v += resid[idx];
                    ((float*)outp)[idx] = v;
                } else if (outmode == 1) {
                    ((unsigned short*)outp)[(size_t)row * N + col] = f2bf(v);
                } else {
                    int sel = col >> 9, hd = col & 511;
                    int h = hd >> 6, dk = hd & 63;
                    int b = row >> 10, l = row & 1023;
                    unsigned short bw = f2bf(v);
                    size_t bh = (size_t)(b * NHEAD + h);
                    if (sel == 0)      qs[(bh * LSEQ + l) * DKD + dk] = bw;
                    else if (sel == 1) ks[(bh * LSEQ + l) * DKD + dk] = bw;
                    else               vts[(bh * DKD + dk) * LSEQ + l] = bw;
                }
            }
        }
    }
}

// ---------------------------------------------------------------------------
// Flash attention v2 — swapped QK^T (S = mfma(K,Q)) so each lane owns one
// q-row (r15): softmax is per-lane + 2 shfl; bias = 4 float4 loads/tile.
// K/V staged via global_load_lds with pre-swizzled source; P exchanged via
// per-wave 2KB XOR-swizzled bf16 LDS buffer (no barrier). Defer-max (THR=8).
// ---------------------------------------------------------------------------
__global__ __launch_bounds__(256) void attn_mfma(
    const unsigned short* __restrict__ Qg, const unsigned short* __restrict__ Kg,
    const unsigned short* __restrict__ Vtg, const float* __restrict__ bias,
    const float* __restrict__ maskF, unsigned short* __restrict__ Ob)
{
    __shared__ uint4 Ks[512];            // [64 keys][8 chunks] linear (src pre-swz)
    __shared__ uint4 Vs[512];            // [64 dk][8 chunks of keys]
    __shared__ unsigned int Pb[2048];    // 4 waves x 16 rows x 64 bf16 (XOR-swz)

    const int t = threadIdx.x;
    const int lane = t & 63, w = t >> 6;
    const int g = lane >> 4, r15 = lane & 15;

    // XCD-aware remap: consecutive bh stay on one XCD for K/V L2 locality
    const int p = blockIdx.x;
    const int logical = (p & 7) * 128 + (p >> 3);
    const int bh = logical >> 4, qt = logical & 15;
    const int b = bh >> 3, h = bh & 7;

    bf8 qf[2];   // B-fragment: col = qrow(r15), k = g*8.. (+32)
    const int qrow = qt * 64 + w * 16 + r15;
    {
        const unsigned short* qp = Qg + ((size_t)bh * LSEQ + qrow) * DKD + g * 8;
        qf[0] = *(const bf8*)qp;
        qf[1] = *(const bf8*)(qp + 32);
    }

    float mrun = -1e30f, lsum = 0.f;
    f4 oacc[4] = {};

    const float* biasRow = bias + ((size_t)b << 20) + (size_t)qrow * LSEQ;
    const float* maskFb  = maskF + b * LSEQ;

    const int sr  = t >> 3;                    // 0..31
    const int chs = (t & 7) ^ (sr & 7);        // pre-swizzled source chunk
    unsigned short* Kl = (unsigned short*)Ks + (w * 8) * 64;
    unsigned short* Vl = (unsigned short*)Vs + (w * 8) * 64;
    unsigned short* Pw = (unsigned short*)&Pb[w * 512];

    for (int kt = 0; kt < 16; ++kt) {
        const int key0 = kt * 64;
        __syncthreads();
        {
            const unsigned short* Kgp = Kg  + ((size_t)bh * LSEQ + key0 + sr) * DKD + chs * 8;
            const unsigned short* Vgp = Vtg + ((size_t)bh * DKD + sr) * LSEQ + key0 + chs * 8;
            gload16(Kgp, Kl);
            gload16(Kgp + (size_t)32 * DKD, Kl + 32 * 64);
            gload16(Vgp, Vl);
            gload16(Vgp + (size_t)32 * LSEQ, Vl + 32 * 64);
        }
        __syncthreads();

        // S^T = K Q : lane holds keys {key0 + m*16 + g*4 + reg} of q-row r15
        f4 sacc[4] = {};
        #pragma unroll
        for (int kk = 0; kk < 2; ++kk)
            #pragma unroll
            for (int m = 0; m < 4; ++m) {
                int row = m * 16 + r15;
                bf8 kf = *(const bf8*)&Ks[row * 8 + ((kk * 4 + g) ^ (row & 7))];
                sacc[m] = __builtin_amdgcn_mfma_f32_16x16x32_bf16(kf, qf[kk], sacc[m], 0, 0, 0);
            }

        // per-lane softmax over 16 keys, reduce across 4 g-lanes (2 shfl)
        float s[16];
        float pmax = -1e30f;
        #pragma unroll
        for (int m = 0; m < 4; ++m) {
            float4 bv = *(const float4*)(biasRow + key0 + m * 16 + g * 4);
            float4 mv = *(const float4*)(maskFb  + key0 + m * 16 + g * 4);
            const float* bvp = (const float*)&bv;
            const float* mvp = (const float*)&mv;
            #pragma unroll
            for (int j = 0; j < 4; ++j) {
                float sv = fmaf(sacc[m][j], 0.125f, bvp[j] + mvp[j]);
                s[m * 4 + j] = sv;
                pmax = fmaxf(pmax, sv);
            }
        }
        pmax = fmaxf(pmax, __shfl_xor(pmax, 16));
        pmax = fmaxf(pmax, __shfl_xor(pmax, 32));

        if (!__all(pmax <= mrun + 8.f)) {        // defer-max (T13)
            float mnew = fmaxf(mrun, pmax);
            float scale = __expf(mrun - mnew);
            lsum *= scale;
            #pragma unroll
            for (int m = 0; m < 4; ++m)
                #pragma unroll
                for (int j = 0; j < 4; ++j) oacc[m][j] *= scale;
            mrun = mnew;
        }

        float psum = 0.f;
        #pragma unroll
        for (int i = 0; i < 16; ++i) { s[i] = __expf(s[i] - mrun); psum += s[i]; }
        psum += __shfl_xor(psum, 16);
        psum += __shfl_xor(psum, 32);
        lsum += psum;

        // P -> per-wave LDS (bf16, XOR-swizzled), no barrier (wave-private)
        #pragma unroll
        for (int m = 0; m < 4; ++m) {
            uint2 pk;
            pk.x = (unsigned)f2bf(s[m * 4 + 0]) | ((unsigned)f2bf(s[m * 4 + 1]) << 16);
            pk.y = (unsigned)f2bf(s[m * 4 + 2]) | ((unsigned)f2bf(s[m * 4 + 3]) << 16);
            int off = (r15 * 128 + m * 32 + g * 8) ^ ((r15 & 7) << 4);
            *(uint2*)((char*)Pw + off) = pk;
        }

        // O^T += V^T P : A = V^T frag (row=d), B = P frag (col=qrow)
        #pragma unroll
        for (int kk = 0; kk < 2; ++kk) {
            int off = (r15 * 128 + kk * 64 + g * 16) ^ ((r15 & 7) << 4);
            bf8 pf = *(const bf8*)((char*)Pw + off);
            #pragma unroll
            for (int m = 0; m < 4; ++m) {
                int row = m * 16 + r15;
                bf8 vf = *(const bf8*)&Vs[row * 8 + ((kk * 4 + g) ^ (row & 7))];
                oacc[m] = __builtin_amdgcn_mfma_f32_16x16x32_bf16(vf, pf, oacc[m], 0, 0, 0);
            }
        }
    }

    // write O: lane owns q-row r15, dims m*16 + g*4 + {0..3}
    {
        float inv = 1.f / lsum;
        unsigned short* op = Ob + ((size_t)b * LSEQ + qrow) * DMODEL + h * DKD;
        #pragma unroll
        for (int m = 0; m < 4; ++m) {
            ushort4 o4;
            o4.x = f2bf(oacc[m][0] * inv);
            o4.y = f2bf(oacc[m][1] * inv);
            o4.z = f2bf(oacc[m][2] * inv);
            o4.w = f2bf(oacc[m][3] * inv);
            *(ushort4*)(op + m * 16 + g * 4) = o4;
        }
    }
}

// ---------------------------------------------------------------------------
// LayerNorm (fp32), optional bf16 secondary output. One wave per row of 512.
// ---------------------------------------------------------------------------
__global__ __launch_bounds__(256) void ln_kernel(
    const float* __restrict__ in, const float* __restrict__ g,
    const float* __restrict__ bt, float* __restrict__ out,
    unsigned short* __restrict__ outb)
{
    const int row  = blockIdx.x * 4 + (threadIdx.x >> 6);
    const int lane = threadIdx.x & 63;
    const float* rp = in + (size_t)row * DMODEL + lane * 8;
    float4 x0 = *(const float4*)rp;
    float4 x1 = *(const float4*)(rp + 4);
    float xs[8] = {x0.x, x0.y, x0.z, x0.w, x1.x, x1.y, x1.z, x1.w};

    float sum = 0.f;
    #pragma unroll
    for (int i = 0; i < 8; ++i) sum += xs[i];
    #pragma unroll
    for (int off = 32; off; off >>= 1) sum += __shfl_xor(sum, off);
    float mu = sum * (1.f / 512.f);

    float vs = 0.f;
    #pragma unroll
    for (int i = 0; i < 8; ++i) { float d = xs[i] - mu; vs += d * d; }
    #pragma unroll
    for (int off = 32; off; off >>= 1) vs += __shfl_xor(vs, off);
    float rs = rsqrtf(vs * (1.f / 512.f) + 1e-5f);

    const float* gp = g  + lane * 8;
    const float* bp = bt + lane * 8;
    float4 g0 = *(const float4*)gp, g1 = *(const float4*)(gp + 4);
    float4 b0 = *(const float4*)bp, b1 = *(const float4*)(bp + 4);
    float gs[8] = {g0.x, g0.y, g0.z, g0.w, g1.x, g1.y, g1.z, g1.w};
    float bs[8] = {b0.x, b0.y, b0.z, b0.w, b1.x, b1.y, b1.z, b1.w};

    float res[8];
    #pragma unroll
    for (int i = 0; i < 8; ++i) res[i] = (xs[i] - mu) * rs * gs[i] + bs[i];

    float* op = out + (size_t)row * DMODEL + lane * 8;
    float4 r0 = {res[0], res[1], res[2], res[3]};
    float4 r1 = {res[4], res[5], res[6], res[7]};
    *(float4*)op       = r0;
    *(float4*)(op + 4) = r1;

    if (outb) {
        unsigned short* ob = outb + (size_t)row * DMODEL + lane * 8;
        ushort4 u0, u1;
        u0.x = f2bf(res[0]); u0.y = f2bf(res[1]); u0.z = f2bf(res[2]); u0.w = f2bf(res[3]);
        u1.x = f2bf(res[4]); u1.y = f2bf(res[5]); u1.z = f2bf(res[6]); u1.w = f2bf(res[7]);
        *(ushort4*)ob       = u0;
        *(ushort4*)(ob + 4) = u1;
    }
}

// ---------------------------------------------------------------------------
extern "C" void kernel_launch(void* const* d_in, const int* in_sizes, int n_in,
                              void* d_out, int out_size, void* d_ws, size_t ws_size,
                              hipStream_t stream)
{
    const float*         x    = (const float*)d_in[0];
    const unsigned char* mask = (const unsigned char*)d_in[1];
    const float*         bias = (const float*)d_in[2];
    const float* Wq = (const float*)d_in[3];
    const float* bq = (const float*)d_in[4];
    const float* Wk = (const float*)d_in[5];
    const float* bk = (const float*)d_in[6];
    const float* Wv = (const float*)d_in[7];
    const float* bv = (const float*)d_in[8];
    const float* Wo = (const float*)d_in[9];
    const float* bo = (const float*)d_in[10];
    const float* ln1g = (const float*)d_in[11];
    const float* ln1b = (const float*)d_in[12];
    const float* W1 = (const float*)d_in[13];
    const float* b1 = (const float*)d_in[14];
    const float* W2 = (const float*)d_in[15];
    const float* b2 = (const float*)d_in[16];
    const float* ln2g = (const float*)d_in[17];
    const float* ln2b = (const float*)d_in[18];

    char* W = (char*)d_ws;
    unsigned short* Qb   = (unsigned short*)(W);                       // 8 MB
    unsigned short* Kb   = (unsigned short*)(W + (8u << 20));          // 8 MB
    unsigned short* Vtb  = (unsigned short*)(W + (16u << 20));         // 8 MB
    unsigned short* Oball= (unsigned short*)(W + (24u << 20));         // 8 MB
    unsigned short* hb   = (unsigned short*)(W);                       // 32 MB (reuses Q/K/Vt/O)
    float*          y12  = (float*)(W + (32u << 20));                  // 16 MB (y1 then y2)
    float*          x1   = (float*)(W + (48u << 20));                  // 16 MB
    unsigned short* xb   = (unsigned short*)(W + (64u << 20));         // 8 MB
    unsigned short* x1b  = xb;                                         // reuse after GEMM1
    unsigned short* Wqkv = (unsigned short*)(W + (72u << 20));         // 1.5 MB
    unsigned short* Wot  = (unsigned short*)(W + (74u << 20));         // 0.5 MB
    unsigned short* W1t  = (unsigned short*)(W + (75u << 20));         // 2 MB
    unsigned short* W2t  = (unsigned short*)(W + (77u << 20));         // 2 MB
    float*          bqkv = (float*)(W + (79u << 20));                  // 6 KB
    float*          maskF= (float*)(W + (79u << 20) + 65536);          // 32 KB
    float*          outp = (float*)d_out;

    // prepass
    conv_bf16<<<dim3(4096), dim3(256), 0, stream>>>(x, xb, NBL * DMODEL);
    transpose_bf16<<<dim3(8, 8),  dim3(256), 0, stream>>>(Wq, Wqkv,          512, 512);
    transpose_bf16<<<dim3(8, 8),  dim3(256), 0, stream>>>(Wk, Wqkv + 262144, 512, 512);
    transpose_bf16<<<dim3(8, 8),  dim3(256), 0, stream>>>(Wv, Wqkv + 524288, 512, 512);
    transpose_bf16<<<dim3(8, 8),  dim3(256), 0, stream>>>(Wo, Wot, 512, 512);
    transpose_bf16<<<dim3(32, 8), dim3(256), 0, stream>>>(W1, W1t, 512, 2048);
    transpose_bf16<<<dim3(8, 32), dim3(256), 0, stream>>>(W2, W2t, 2048, 512);
    concat3<<<dim3(6), dim3(256), 0, stream>>>(bq, bk, bv, bqkv);
    maskf_kernel<<<dim3(32), dim3(256), 0, stream>>>(mask, maskF, NBL);

    // QKV fused projection, scatter to Q/K [bh,l,dk] and V^T [bh,dk,l]
    mfma_gemm<<<dim3(12, 64), dim3(256), 0, stream>>>(
        xb, Wqkv, bqkv, nullptr, nullptr, NBL, 1536, 512, 0, 2, Qb, Kb, Vtb);

    // attention
    attn_mfma<<<dim3(1024), dim3(256), 0, stream>>>(Qb, Kb, Vtb, bias, maskF, Oball);

    // out projection + residual(x) -> y1 (fp32)
    mfma_gemm<<<dim3(4, 64), dim3(256), 0, stream>>>(
        Oball, Wot, bo, x, y12, NBL, 512, 512, 0, 0, nullptr, nullptr, nullptr);

    // LN1 -> x1 (fp32) + x1b (bf16)
    ln_kernel<<<dim3(NBL / 4), dim3(256), 0, stream>>>(y12, ln1g, ln1b, x1, x1b);

    // FFN1: relu(x1 @ W1 + b1) -> hb (bf16)
    mfma_gemm<<<dim3(16, 64), dim3(256), 0, stream>>>(
        x1b, W1t, b1, nullptr, hb, NBL, 2048, 512, 1, 1, nullptr, nullptr, nullptr);

    // FFN2: hb @ W2 + b2 + x1 -> y2 (fp32)
    mfma_gemm<<<dim3(4, 64), dim3(256), 0, stream>>>(
        hb, W2t, b2, x1, y12, NBL, 512, 2048, 0, 0, nullptr, nullptr, nullptr);

    // LN2 -> output
    ln_kernel<<<dim3(NBL / 4), dim3(256), 0, stream>>>(y12, ln2g, ln2b, outp, nullptr);
}

// Round 7
// 358.434 us; speedup vs baseline: 4.9813x; 1.0788x over previous
//
#include <hip/hip_runtime.h>
#include <math.h>

#define NHEAD 8
#define DKD 64
#define DMODEL 512
#define LSEQ 1024
#define NBL 8192          // B*L

typedef __attribute__((ext_vector_type(8))) short bf8;   // 8 x bf16 (4 VGPRs)
typedef __attribute__((ext_vector_type(4))) float f4;    // MFMA accumulator

__device__ inline unsigned short f2bf(float f) {
    union { float f; unsigned u; } v; v.f = f;
    unsigned r = v.u + 0x7FFFu + ((v.u >> 16) & 1u);   // RNE
    return (unsigned short)(r >> 16);
}

// v_cvt_pk_bf16_f32: pack two fp32 -> two bf16 in one u32 (T12 recipe)
__device__ __forceinline__ unsigned cvtpk(float lo, float hi) {
    unsigned r;
    asm("v_cvt_pk_bf16_f32 %0, %1, %2" : "=v"(r) : "v"(lo), "v"(hi));
    return r;
}

// async global->LDS, 16B per lane. LDS dest = wave-uniform base + lane*16.
__device__ __forceinline__ void gload16(const void* g, void* l) {
    __builtin_amdgcn_global_load_lds(
        (const __attribute__((address_space(1))) unsigned int*)g,
        (__attribute__((address_space(3))) unsigned int*)l, 16, 0, 0);
}

// ---------------------------------------------------------------------------
// prepass: fp32 -> bf16 elementwise (x)
// ---------------------------------------------------------------------------
__global__ __launch_bounds__(256) void conv_bf16(
    const float* __restrict__ in, unsigned short* __restrict__ out, int n)
{
    int i = (blockIdx.x * 256 + threadIdx.x) * 4;
    if (i >= n) return;
    float4 v = *(const float4*)(in + i);
    ushort4 o;
    o.x = f2bf(v.x); o.y = f2bf(v.y); o.z = f2bf(v.z); o.w = f2bf(v.w);
    *(ushort4*)(out + i) = o;
}

// ---------------------------------------------------------------------------
// prepass: biasM[b][q][k] = bias + (mask[b][k] ? -1e30 : 0)
// ---------------------------------------------------------------------------
__global__ __launch_bounds__(256) void biasm_kernel(
    const float* __restrict__ bias, const unsigned char* __restrict__ mask,
    float* __restrict__ o)
{
    int i = blockIdx.x * 256 + threadIdx.x;     // float4 index
    int flat = i * 4;
    int b = flat >> 20;
    int k = flat & 1023;
    float4 v = ((const float4*)bias)[i];
    uchar4 mk = *(const uchar4*)(mask + b * 1024 + k);
    if (mk.x) v.x = -1e30f;
    if (mk.y) v.y = -1e30f;
    if (mk.z) v.z = -1e30f;
    if (mk.w) v.w = -1e30f;
    ((float4*)o)[i] = v;
}

// ---------------------------------------------------------------------------
// prepass: all weight transposes + bias concat in ONE launch (769 blocks)
// ---------------------------------------------------------------------------
__device__ __forceinline__ void do_transpose(
    const float* __restrict__ W, unsigned short* __restrict__ Wt,
    int K, int N, int bx, int by)
{
    __shared__ float tile[64][65];
    const int k0 = by * 64, n0 = bx * 64;
    const int c = threadIdx.x & 63, r0 = (threadIdx.x >> 6) * 16;
    #pragma unroll
    for (int i = 0; i < 16; ++i)
        tile[r0 + i][c] = W[(size_t)(k0 + r0 + i) * N + n0 + c];
    __syncthreads();
    #pragma unroll
    for (int i = 0; i < 16; ++i)
        Wt[(size_t)(n0 + r0 + i) * K + k0 + c] = f2bf(tile[c][r0 + i]);
}

__global__ __launch_bounds__(256) void prep_weights(
    const float* __restrict__ Wq, const float* __restrict__ Wk,
    const float* __restrict__ Wv, const float* __restrict__ Wo,
    const float* __restrict__ W1, const float* __restrict__ W2,
    const float* __restrict__ bq, const float* __restrict__ bk,
    const float* __restrict__ bv,
    unsigned short* __restrict__ Wqkv, unsigned short* __restrict__ Wot,
    unsigned short* __restrict__ W1t, unsigned short* __restrict__ W2t,
    float* __restrict__ bqkv)
{
    int j = blockIdx.x;
    if (j < 256) {                               // four 512x512 transposes
        int which = j >> 6, tt = j & 63;
        const float* src = which == 0 ? Wq : which == 1 ? Wk : which == 2 ? Wv : Wo;
        unsigned short* dst = which == 0 ? Wqkv : which == 1 ? (Wqkv + 262144)
                            : which == 2 ? (Wqkv + 524288) : Wot;
        do_transpose(src, dst, 512, 512, tt & 7, tt >> 3);
    } else if (j < 512) {                        // W1: [512,2048]
        int tt = j - 256;
        do_transpose(W1, W1t, 512, 2048, tt & 31, tt >> 5);
    } else if (j < 768) {                        // W2: [2048,512]
        int tt = j - 512;
        do_transpose(W2, W2t, 2048, 512, tt & 7, tt >> 3);
    } else {                                     // concat qkv biases
        for (int c = threadIdx.x; c < 1536; c += 256)
            bqkv[c] = c < 512 ? bq[c] : c < 1024 ? bk[c - 512] : bv[c - 1024];
    }
}

// ---------------------------------------------------------------------------
// bf16 MFMA GEMM: C[M,N] = A[M,K] @ Bt[N,K]^T + bias. Tile 128 x BN, 4 waves.
// BK=64; global_load_lds (16B) with pre-swizzled source chunk; linear LDS;
// XOR-swizzled reads -> conflict-free ds_read_b128.
// outmode: 0 = fp32 [M,N] (+resid), 1 = bf16 [M,N] (+relu), 2 = QKV scatter
// ---------------------------------------------------------------------------
template<int BN>
__global__ __launch_bounds__(256) void mfma_gemm(
    const unsigned short* __restrict__ A, const unsigned short* __restrict__ Bt,
    const float* __restrict__ bias, const float* __restrict__ resid,
    void* __restrict__ outp, int M, int N, int K, int relu, int outmode,
    unsigned short* __restrict__ qs, unsigned short* __restrict__ ks,
    unsigned short* __restrict__ vts)
{
    __shared__ uint4 As[1024];          // 128 rows x 8 chunks
    __shared__ uint4 Bs[BN * 8];        // BN rows x 8 chunks
    constexpr int NB = BN / 32;         // acc cols per wave

    const int t = threadIdx.x;
    const int lane = t & 63, w = t >> 6;
    const int g = lane >> 4, r15 = lane & 15;
    const int wr = w >> 1, wc = w & 1;
    const int rowBase = blockIdx.y * 128, colBase = blockIdx.x * BN;

    f4 acc[4][NB] = {};

    const int r   = t >> 3;                    // w*8 + (lane>>3)
    const int chs = (t & 7) ^ (r & 7);         // pre-swizzled source chunk
    unsigned short* Al = (unsigned short*)As + (w * 8) * 64;
    unsigned short* Bl = (unsigned short*)Bs + (w * 8) * 64;

    for (int k0 = 0; k0 < K; k0 += 64) {
        __syncthreads();
        {
            const unsigned short* Ag = A  + (size_t)(rowBase + r) * K + k0 + chs * 8;
            const unsigned short* Bg = Bt + (size_t)(colBase + r) * K + k0 + chs * 8;
            #pragma unroll
            for (int p = 0; p < 4; ++p)
                gload16(Ag + (size_t)(p * 32) * K, Al + p * 32 * 64);
            #pragma unroll
            for (int p = 0; p < BN / 32; ++p)
                gload16(Bg + (size_t)(p * 32) * K, Bl + p * 32 * 64);
        }
        __syncthreads();
        #pragma unroll
        for (int kk = 0; kk < 2; ++kk) {
            bf8 af[4], bfr[NB];
            #pragma unroll
            for (int m = 0; m < 4; ++m) {
                int ra = wr * 64 + m * 16 + r15;
                af[m] = *(const bf8*)&As[ra * 8 + ((kk * 4 + g) ^ (ra & 7))];
            }
            #pragma unroll
            for (int n = 0; n < NB; ++n) {
                int rb = wc * (BN / 2) + n * 16 + r15;
                bfr[n] = *(const bf8*)&Bs[rb * 8 + ((kk * 4 + g) ^ (rb & 7))];
            }
            #pragma unroll
            for (int m = 0; m < 4; ++m)
                #pragma unroll
                for (int n = 0; n < NB; ++n)
                    acc[m][n] = __builtin_amdgcn_mfma_f32_16x16x32_bf16(
                        af[m], bfr[n], acc[m][n], 0, 0, 0);
        }
    }

    #pragma unroll
    for (int m = 0; m < 4; ++m) {
        #pragma unroll
        for (int n = 0; n < NB; ++n) {
            int col = colBase + wc * (BN / 2) + n * 16 + r15;
            float bv = bias[col];
            #pragma unroll
            for (int rr = 0; rr < 4; ++rr) {
                int row = rowBase + wr * 64 + m * 16 + g * 4 + rr;
                float v = acc[m][n][rr] + bv;
                if (relu) v = fmaxf(v, 0.f);
                if (outmode == 0) {
                    size_t idx = (size_t)row * N + col;
                    if (resid) v += resid[idx];
                    ((float*)outp)[idx] = v;
                } else if (outmode == 1) {
                    ((unsigned short*)outp)[(size_t)row * N + col] = f2bf(v);
                } else {
                    int sel = col >> 9, hd = col & 511;
                    int h = hd >> 6, dk = hd & 63;
                    int b = row >> 10, l = row & 1023;
                    unsigned short bw = f2bf(v);
                    size_t bh = (size_t)(b * NHEAD + h);
                    if (sel == 0)      qs[(bh * LSEQ + l) * DKD + dk] = bw;
                    else if (sel == 1) ks[(bh * LSEQ + l) * DKD + dk] = bw;
                    else               vts[(bh * DKD + dk) * LSEQ + l] = bw;
                }
            }
        }
    }
}

// ---------------------------------------------------------------------------
// Flash attention v3. Block = 128 q-rows of one (b,h), 4 waves x 32 rows
// (2 q-groups of 16 -> K/V LDS fragment reads amortized 2x). Swapped QK^T
// (lane owns one q-row). Double-buffered K/V via global_load_lds (2-phase:
// stage(next) -> compute(cur) -> 1 barrier/tile). Mask pre-folded into biasM.
// P pack via v_cvt_pk_bf16_f32; per-wave XOR-swizzled P buffer (no barrier).
// ---------------------------------------------------------------------------
__global__ __launch_bounds__(256) void attn_mfma(
    const unsigned short* __restrict__ Qg, const unsigned short* __restrict__ Kg,
    const unsigned short* __restrict__ Vtg, const float* __restrict__ biasM,
    unsigned short* __restrict__ Ob)
{
    __shared__ uint4 Ks[2][512];         // [buf][64 keys x 8 chunks]
    __shared__ uint4 Vs[2][512];         // [buf][64 dk x 8 key-chunks]
    __shared__ unsigned int Pb[4096];    // 4 waves x 32 rows x 64 keys bf16

    const int t = threadIdx.x;
    const int lane = t & 63, w = t >> 6;
    const int g = lane >> 4, r15 = lane & 15;

    // XCD-aware remap (512 blocks, 64 per XCD chunk)
    const int p = blockIdx.x;
    const int logical = (p & 7) * 64 + (p >> 3);
    const int bh = logical >> 3, qt = logical & 7;
    const int b = bh >> 3, h = bh & 7;
    const int qbase = qt * 128 + w * 32;

    bf8 qf[2][2];
    #pragma unroll
    for (int u = 0; u < 2; ++u) {
        const unsigned short* qp = Qg + ((size_t)bh * LSEQ + qbase + u * 16 + r15) * DKD + g * 8;
        qf[u][0] = *(const bf8*)qp;
        qf[u][1] = *(const bf8*)(qp + 32);
    }

    float mrun[2] = {-1e30f, -1e30f}, lsum[2] = {0.f, 0.f};
    f4 oacc[2][4] = {};

    const int sr  = t >> 3;                    // 0..31
    const int chs = (t & 7) ^ (sr & 7);        // pre-swizzled source chunk
    unsigned int* Pw = Pb + w * 1024;

    const size_t kBase = (size_t)bh * LSEQ * DKD;   // K rows
    const size_t vBase = (size_t)bh * DKD * LSEQ;   // V^T rows

    // prologue: stage tile 0 into buf 0
    {
        const unsigned short* Kgp = Kg  + kBase + (size_t)sr * DKD + chs * 8;
        const unsigned short* Vgp = Vtg + vBase + (size_t)sr * LSEQ + chs * 8;
        unsigned short* Kl = (unsigned short*)Ks[0] + (w * 8) * 64;
        unsigned short* Vl = (unsigned short*)Vs[0] + (w * 8) * 64;
        gload16(Kgp, Kl);
        gload16(Kgp + (size_t)32 * DKD, Kl + 32 * 64);
        gload16(Vgp, Vl);
        gload16(Vgp + (size_t)32 * LSEQ, Vl + 32 * 64);
    }
    __syncthreads();

    for (int kt = 0; kt < 16; ++kt) {
        const int cur = kt & 1;
        const int key0 = kt * 64;
        if (kt < 15) {   // stage next tile into other buffer (overlaps compute)
            const int nk0 = key0 + 64;
            const unsigned short* Kgp = Kg  + kBase + (size_t)(nk0 + sr) * DKD + chs * 8;
            const unsigned short* Vgp = Vtg + vBase + (size_t)sr * LSEQ + nk0 + chs * 8;
            unsigned short* Kl = (unsigned short*)Ks[cur ^ 1] + (w * 8) * 64;
            unsigned short* Vl = (unsigned short*)Vs[cur ^ 1] + (w * 8) * 64;
            gload16(Kgp, Kl);
            gload16(Kgp + (size_t)32 * DKD, Kl + 32 * 64);
            gload16(Vgp, Vl);
            gload16(Vgp + (size_t)32 * LSEQ, Vl + 32 * 64);
        }

        // S^T = K Q for both q-groups (K frags shared)
        f4 sacc[2][4] = {};
        #pragma unroll
        for (int kk = 0; kk < 2; ++kk)
            #pragma unroll
            for (int m = 0; m < 4; ++m) {
                int row = m * 16 + r15;
                bf8 kf = *(const bf8*)&Ks[cur][row * 8 + ((kk * 4 + g) ^ (row & 7))];
                sacc[0][m] = __builtin_amdgcn_mfma_f32_16x16x32_bf16(kf, qf[0][kk], sacc[0][m], 0, 0, 0);
                sacc[1][m] = __builtin_amdgcn_mfma_f32_16x16x32_bf16(kf, qf[1][kk], sacc[1][m], 0, 0, 0);
            }

        // softmax per q-group (per-lane over 16 keys + 2 shfl)
        #pragma unroll
        for (int u = 0; u < 2; ++u) {
            const float* biasRow = biasM + ((size_t)b << 20)
                                 + (size_t)(qbase + u * 16 + r15) * LSEQ + key0;
            float s[16];
            float pmax = -1e30f;
            #pragma unroll
            for (int m = 0; m < 4; ++m) {
                float4 bv = *(const float4*)(biasRow + m * 16 + g * 4);
                const float* bvp = (const float*)&bv;
                #pragma unroll
                for (int j = 0; j < 4; ++j) {
                    float sv = fmaf(sacc[u][m][j], 0.125f, bvp[j]);
                    s[m * 4 + j] = sv;
                    pmax = fmaxf(pmax, sv);
                }
            }
            pmax = fmaxf(pmax, __shfl_xor(pmax, 16));
            pmax = fmaxf(pmax, __shfl_xor(pmax, 32));

            if (!__all(pmax <= mrun[u] + 8.f)) {     // defer-max (T13)
                float mnew = fmaxf(mrun[u], pmax);
                float scale = __expf(mrun[u] - mnew);
                lsum[u] *= scale;
                #pragma unroll
                for (int m = 0; m < 4; ++m)
                    #pragma unroll
                    for (int j = 0; j < 4; ++j) oacc[u][m][j] *= scale;
                mrun[u] = mnew;
            }

            float psum = 0.f;
            #pragma unroll
            for (int i = 0; i < 16; ++i) { s[i] = __expf(s[i] - mrun[u]); psum += s[i]; }
            psum += __shfl_xor(psum, 16);
            psum += __shfl_xor(psum, 32);
            lsum[u] += psum;

            // pack P -> per-wave LDS (bf16, XOR-swizzled), wave-private
            #pragma unroll
            for (int m = 0; m < 4; ++m) {
                uint2 pk;
                pk.x = cvtpk(s[m * 4 + 0], s[m * 4 + 1]);
                pk.y = cvtpk(s[m * 4 + 2], s[m * 4 + 3]);
                int off = ((u * 16 + r15) * 128 + m * 32 + g * 8) ^ ((r15 & 7) << 4);
                *(uint2*)((char*)Pw + off) = pk;
            }
        }

        // O^T += V^T P (V frags shared across q-groups)
        #pragma unroll
        for (int kk = 0; kk < 2; ++kk) {
            bf8 pf[2];
            #pragma unroll
            for (int u = 0; u < 2; ++u) {
                int off = ((u * 16 + r15) * 128 + kk * 64 + g * 16) ^ ((r15 & 7) << 4);
                pf[u] = *(const bf8*)((char*)Pw + off);
            }
            #pragma unroll
            for (int m = 0; m < 4; ++m) {
                int row = m * 16 + r15;
                bf8 vf = *(const bf8*)&Vs[cur][row * 8 + ((kk * 4 + g) ^ (row & 7))];
                oacc[0][m] = __builtin_amdgcn_mfma_f32_16x16x32_bf16(vf, pf[0], oacc[0][m], 0, 0, 0);
                oacc[1][m] = __builtin_amdgcn_mfma_f32_16x16x32_bf16(vf, pf[1], oacc[1][m], 0, 0, 0);
            }
        }
        __syncthreads();   // staged tile ready; all waves done with cur buffers
    }

    #pragma unroll
    for (int u = 0; u < 2; ++u) {
        float inv = 1.f / lsum[u];
        unsigned short* op = Ob + ((size_t)b * LSEQ + qbase + u * 16 + r15) * DMODEL + h * DKD;
        #pragma unroll
        for (int m = 0; m < 4; ++m) {
            ushort4 o4;
            o4.x = f2bf(oacc[u][m][0] * inv);
            o4.y = f2bf(oacc[u][m][1] * inv);
            o4.z = f2bf(oacc[u][m][2] * inv);
            o4.w = f2bf(oacc[u][m][3] * inv);
            *(ushort4*)(op + m * 16 + g * 4) = o4;
        }
    }
}

// ---------------------------------------------------------------------------
// LayerNorm (fp32), optional bf16 secondary output. One wave per row of 512.
// ---------------------------------------------------------------------------
__global__ __launch_bounds__(256) void ln_kernel(
    const float* __restrict__ in, const float* __restrict__ g,
    const float* __restrict__ bt, float* __restrict__ out,
    unsigned short* __restrict__ outb)
{
    const int row  = blockIdx.x * 4 + (threadIdx.x >> 6);
    const int lane = threadIdx.x & 63;
    const float* rp = in + (size_t)row * DMODEL + lane * 8;
    float4 x0 = *(const float4*)rp;
    float4 x1 = *(const float4*)(rp + 4);
    float xs[8] = {x0.x, x0.y, x0.z, x0.w, x1.x, x1.y, x1.z, x1.w};

    float sum = 0.f;
    #pragma unroll
    for (int i = 0; i < 8; ++i) sum += xs[i];
    #pragma unroll
    for (int off = 32; off; off >>= 1) sum += __shfl_xor(sum, off);
    float mu = sum * (1.f / 512.f);

    float vs = 0.f;
    #pragma unroll
    for (int i = 0; i < 8; ++i) { float d = xs[i] - mu; vs += d * d; }
    #pragma unroll
    for (int off = 32; off; off >>= 1) vs += __shfl_xor(vs, off);
    float rs = rsqrtf(vs * (1.f / 512.f) + 1e-5f);

    const float* gp = g  + lane * 8;
    const float* bp = bt + lane * 8;
    float4 g0 = *(const float4*)gp, g1 = *(const float4*)(gp + 4);
    float4 b0 = *(const float4*)bp, b1 = *(const float4*)(bp + 4);
    float gs[8] = {g0.x, g0.y, g0.z, g0.w, g1.x, g1.y, g1.z, g1.w};
    float bs[8] = {b0.x, b0.y, b0.z, b0.w, b1.x, b1.y, b1.z, b1.w};

    float res[8];
    #pragma unroll
    for (int i = 0; i < 8; ++i) res[i] = (xs[i] - mu) * rs * gs[i] + bs[i];

    float* op = out + (size_t)row * DMODEL + lane * 8;
    float4 r0 = {res[0], res[1], res[2], res[3]};
    float4 r1 = {res[4], res[5], res[6], res[7]};
    *(float4*)op       = r0;
    *(float4*)(op + 4) = r1;

    if (outb) {
        unsigned short* ob = outb + (size_t)row * DMODEL + lane * 8;
        ushort4 u0, u1;
        u0.x = f2bf(res[0]); u0.y = f2bf(res[1]); u0.z = f2bf(res[2]); u0.w = f2bf(res[3]);
        u1.x = f2bf(res[4]); u1.y = f2bf(res[5]); u1.z = f2bf(res[6]); u1.w = f2bf(res[7]);
        *(ushort4*)ob       = u0;
        *(ushort4*)(ob + 4) = u1;
    }
}

// ---------------------------------------------------------------------------
extern "C" void kernel_launch(void* const* d_in, const int* in_sizes, int n_in,
                              void* d_out, int out_size, void* d_ws, size_t ws_size,
                              hipStream_t stream)
{
    const float*         x    = (const float*)d_in[0];
    const unsigned char* mask = (const unsigned char*)d_in[1];
    const float*         bias = (const float*)d_in[2];
    const float* Wq = (const float*)d_in[3];
    const float* bq = (const float*)d_in[4];
    const float* Wk = (const float*)d_in[5];
    const float* bk = (const float*)d_in[6];
    const float* Wv = (const float*)d_in[7];
    const float* bv = (const float*)d_in[8];
    const float* Wo = (const float*)d_in[9];
    const float* bo = (const float*)d_in[10];
    const float* ln1g = (const float*)d_in[11];
    const float* ln1b = (const float*)d_in[12];
    const float* W1 = (const float*)d_in[13];
    const float* b1 = (const float*)d_in[14];
    const float* W2 = (const float*)d_in[15];
    const float* b2 = (const float*)d_in[16];
    const float* ln2g = (const float*)d_in[17];
    const float* ln2b = (const float*)d_in[18];

    char* W = (char*)d_ws;
    unsigned short* Qb   = (unsigned short*)(W);                 // 8 MB   [dead after attn]
    unsigned short* Kb   = (unsigned short*)(W + (8u << 20));    // 8 MB
    unsigned short* Vtb  = (unsigned short*)(W + (16u << 20));   // 8 MB
    unsigned short* Oball= (unsigned short*)(W + (24u << 20));   // 8 MB   [dead after out-proj]
    unsigned short* hb   = (unsigned short*)(W);                 // 32 MB  (reuses Q/K/Vt/O)
    float*          biasM= (float*)(W + (32u << 20));            // 33.5 MB [dead after attn]
    float*          y12  = (float*)(W + (32u << 20));            // 16 MB  (reuses biasM lo)
    float*          x1   = (float*)(W + (48u << 20));            // 16 MB  (reuses biasM hi)
    unsigned short* xb   = (unsigned short*)(W + (66u << 20));   // 8 MB
    unsigned short* x1b  = xb;                                   // reuse after QKV GEMM
    unsigned short* Wqkv = (unsigned short*)(W + (74u << 20));   // 1.5 MB
    unsigned short* Wot  = (unsigned short*)(W + (76u << 20));   // 0.5 MB
    unsigned short* W1t  = (unsigned short*)(W + (77u << 20));   // 2 MB
    unsigned short* W2t  = (unsigned short*)(W + (79u << 20));   // 2 MB
    float*          bqkv = (float*)(W + (81u << 20));            // 6 KB
    float*          outp = (float*)d_out;

    // prepass (3 launches)
    conv_bf16<<<dim3(4096), dim3(256), 0, stream>>>(x, xb, NBL * DMODEL);
    prep_weights<<<dim3(769), dim3(256), 0, stream>>>(
        Wq, Wk, Wv, Wo, W1, W2, bq, bk, bv, Wqkv, Wot, W1t, W2t, bqkv);
    biasm_kernel<<<dim3(8192), dim3(256), 0, stream>>>(bias, mask, biasM);

    // QKV fused projection, scatter to Q/K [bh,l,dk] and V^T [bh,dk,l]
    mfma_gemm<128><<<dim3(12, 64), dim3(256), 0, stream>>>(
        xb, Wqkv, bqkv, nullptr, nullptr, NBL, 1536, 512, 0, 2, Qb, Kb, Vtb);

    // attention (512 blocks x 128 q-rows)
    attn_mfma<<<dim3(512), dim3(256), 0, stream>>>(Qb, Kb, Vtb, biasM, Oball);

    // out projection + residual(x) -> y1 (fp32); BN=64 -> 512 blocks
    mfma_gemm<64><<<dim3(8, 64), dim3(256), 0, stream>>>(
        Oball, Wot, bo, x, y12, NBL, 512, 512, 0, 0, nullptr, nullptr, nullptr);

    // LN1 -> x1 (fp32) + x1b (bf16)
    ln_kernel<<<dim3(NBL / 4), dim3(256), 0, stream>>>(y12, ln1g, ln1b, x1, x1b);

    // FFN1: relu(x1 @ W1 + b1) -> hb (bf16)
    mfma_gemm<128><<<dim3(16, 64), dim3(256), 0, stream>>>(
        x1b, W1t, b1, nullptr, hb, NBL, 2048, 512, 1, 1, nullptr, nullptr, nullptr);

    // FFN2: hb @ W2 + b2 + x1 -> y2 (fp32); BN=64 -> 512 blocks
    mfma_gemm<64><<<dim3(8, 64), dim3(256), 0, stream>>>(
        hb, W2t, b2, x1, y12, NBL, 512, 2048, 0, 0, nullptr, nullptr, nullptr);

    // LN2 -> output
    ln_kernel<<<dim3(NBL / 4), dim3(256), 0, stream>>>(y12, ln2g, ln2b, outp, nullptr);
}